// Round 7
// baseline (184.636 us; speedup 1.0000x reference)
//
#include <hip/hip_runtime.h>

// Problem constants (from reference): B=4, S=2048, V=64, D=1024, P=8, H=42, K=49152
#define BB 4
#define SS 2048
#define VV 64
#define DD 1024
#define PP 8
#define HH 42
#define KK 49152

static constexpr float F_EPS = 1e-12f;
// n[b,s,p] = c/max(sqrt(S)*c,eps) = 1/sqrt(S) if c>0 else 0, so the softmax
// weight (Z cancels in cos) is exp(n) = ALPHA if dot>0 else 1.
static constexpr float ALPHA = 1.02234304f;

// ---------------------------------------------------------------------------
// kU fused (512 threads): grid (192, 4).
// Blocks x<64: U-pass for (b=y, s-chunk of 32 rows):
//   phase1: u = e/max(2|e|,eps) staged in LDS (32 KB).
//   phase2: each of 8 waves computes 4 row-dots (j-loop, 8 p per lane-oct,
//           27 swizzles/row), writes w = dot>0 ? ALPHA : 1 to w_lds (1 KB).
//   phase3: thread owns float2 d-column; U-partial over the 32 rows
//           (ctx re-read is block-local L2-hot); store to part (8 MB).
// Blocks x>=64: h_all row r = (x-64)*4 + y: tanh(tables_row . w1 + b1),
//   512 threads = 8 d-octants of 128.
// ---------------------------------------------------------------------------
__global__ __launch_bounds__(512) void kU_fused(
    const float* __restrict__ ctx, const float* __restrict__ lora,
    const float* __restrict__ tables, const float* __restrict__ w1,
    const float* __restrict__ b1, float* __restrict__ part,
    float* __restrict__ h_all) {
  __shared__ float smem[PP * DD + 16 + 32 * PP];  // 33 KB
  const int t = threadIdx.x;
  const int b = blockIdx.y;
  if (blockIdx.x < 64) {
    const int chunk = blockIdx.x;
    float* u_lds = smem;
    float* w_lds = smem + PP * DD + 16;
    for (int i = t; i < PP * DD; i += 512) {
      float e = lora[i];
      u_lds[i] = e / fmaxf(2.0f * fabsf(e), F_EPS);
    }
    __syncthreads();
    const int wave = t >> 6, lane = t & 63;
    const int rbase = b * SS + chunk * 32 + wave * 4;
    const float4* ctx4 = (const float4*)ctx;
    const float4* u4 = (const float4*)u_lds;
    float dot[4][PP];
    #pragma unroll
    for (int i = 0; i < 4; ++i)
      #pragma unroll
      for (int p = 0; p < PP; ++p) dot[i][p] = 0.f;
    #pragma unroll
    for (int j = 0; j < 4; ++j) {
      float4 c[4];
      #pragma unroll
      for (int i = 0; i < 4; ++i)
        c[i] = ctx4[(size_t)(rbase + i) * 256 + j * 64 + lane];
      #pragma unroll
      for (int p = 0; p < PP; ++p) {
        float4 u = u4[p * 256 + j * 64 + lane];
        #pragma unroll
        for (int i = 0; i < 4; ++i)
          dot[i][p] += c[i].x * u.x + c[i].y * u.y + c[i].z * u.z + c[i].w * u.w;
      }
    }
    const int sel = lane & 7;
    #pragma unroll
    for (int i = 0; i < 4; ++i) {
      float d0 = dot[i][0], d1 = dot[i][1], d2 = dot[i][2], d3 = dot[i][3];
      float d4 = dot[i][4], d5 = dot[i][5], d6 = dot[i][6], d7 = dot[i][7];
      #pragma unroll
      for (int m = 1; m <= 4; m <<= 1) {
        d0 += __shfl_xor(d0, m, 64); d1 += __shfl_xor(d1, m, 64);
        d2 += __shfl_xor(d2, m, 64); d3 += __shfl_xor(d3, m, 64);
        d4 += __shfl_xor(d4, m, 64); d5 += __shfl_xor(d5, m, 64);
        d6 += __shfl_xor(d6, m, 64); d7 += __shfl_xor(d7, m, 64);
      }
      float v = d0;
      v = (sel == 1) ? d1 : v; v = (sel == 2) ? d2 : v;
      v = (sel == 3) ? d3 : v; v = (sel == 4) ? d4 : v;
      v = (sel == 5) ? d5 : v; v = (sel == 6) ? d6 : v;
      v = (sel == 7) ? d7 : v;
      v += __shfl_xor(v, 8, 64);
      v += __shfl_xor(v, 16, 64);
      v += __shfl_xor(v, 32, 64);
      if (lane < PP)
        w_lds[(wave * 4 + i) * PP + lane] = (v > 0.0f) ? ALPHA : 1.0f;
    }
    __syncthreads();
    // phase 3: weighted accumulation, thread owns d-cols {2t, 2t+1}
    float2 acc[PP];
    #pragma unroll
    for (int p = 0; p < PP; ++p) acc[p] = make_float2(0.f, 0.f);
    const float2* ctx2 = (const float2*)ctx;
    const float4* w4 = (const float4*)w_lds;
    #pragma unroll 4
    for (int sl = 0; sl < 32; ++sl) {
      float2 c = ctx2[(size_t)(b * SS + chunk * 32 + sl) * 512 + t];
      float4 wa = w4[sl * 2];
      float4 wb = w4[sl * 2 + 1];
      float w[PP] = {wa.x, wa.y, wa.z, wa.w, wb.x, wb.y, wb.z, wb.w};
      #pragma unroll
      for (int p = 0; p < PP; ++p) {
        acc[p].x += w[p] * c.x;
        acc[p].y += w[p] * c.y;
      }
    }
    float2* part2 = (float2*)part;
    #pragma unroll
    for (int p = 0; p < PP; ++p)
      part2[(size_t)((b * 64 + chunk) * PP + p) * 512 + t] = acc[p];
  } else {
    // ---------------- h_all row (512 threads, 8 octants) ----------------
    float* row_lds = smem;            // DD floats
    float* partial = smem + DD;       // 512 floats
    const int r = (blockIdx.x - 64) * 4 + b;
    ((float2*)row_lds)[t] = ((const float2*)(tables + (size_t)r * DD))[t];
    __syncthreads();
    const int h = t & 63, q = t >> 6;  // q in 0..7, 128-d octant
    float acc = 0.0f;
    if (h < HH) {
      const int d0 = q * 128;
      #pragma unroll 8
      for (int dl = 0; dl < 128; ++dl) {
        acc += row_lds[d0 + dl] * w1[(size_t)(d0 + dl) * HH + h];
      }
    }
    partial[q * 64 + h] = acc;
    __syncthreads();
    if (t < HH) {
      float s = 0.0f;
      #pragma unroll
      for (int q8 = 0; q8 < 8; ++q8) s += partial[q8 * 64 + t];
      h_all[(size_t)r * HH + t] = tanhf(s + b1[t]);
    }
  }
}

// ---------------------------------------------------------------------------
// K4: per (p,b): reduce 64 chunk-partials -> U, cos = <e,U>/max(|e||U|,1e-8)
// (U is the unnormalized a_v; Z>0 cancels, clamp cannot bind at |U|~4e4)
// ---------------------------------------------------------------------------
__global__ __launch_bounds__(256) void k4_cos(
    const float* __restrict__ part, const float* __restrict__ lora,
    float* __restrict__ cos_ws) {
  const int t = threadIdx.x;
  const int p = blockIdx.x, b = blockIdx.y;
  const float4* part4 = (const float4*)part;
  float4 av = make_float4(0.f, 0.f, 0.f, 0.f);
  #pragma unroll 8
  for (int c = 0; c < 64; ++c) {
    float4 x = part4[(size_t)((b * 64 + c) * PP + p) * 256 + t];
    av.x += x.x; av.y += x.y; av.z += x.z; av.w += x.w;
  }
  float4 e = ((const float4*)lora)[p * 256 + t];
  float dt = av.x * e.x + av.y * e.y + av.z * e.z + av.w * e.w;
  float a2 = av.x * av.x + av.y * av.y + av.z * av.z + av.w * av.w;
  float e2 = e.x * e.x + e.y * e.y + e.z * e.z + e.w * e.w;
  #pragma unroll
  for (int m = 32; m >= 1; m >>= 1) {
    dt += __shfl_xor(dt, m, 64);
    a2 += __shfl_xor(a2, m, 64);
    e2 += __shfl_xor(e2, m, 64);
  }
  __shared__ float red[4][3];
  const int wave = t >> 6, lane = t & 63;
  if (lane == 0) { red[wave][0] = dt; red[wave][1] = a2; red[wave][2] = e2; }
  __syncthreads();
  if (t == 0) {
    float Dv = red[0][0] + red[1][0] + red[2][0] + red[3][0];
    float Av = red[0][1] + red[1][1] + red[2][1] + red[3][1];
    float Ev = red[0][2] + red[1][2] + red[2][2] + red[3][2];
    cos_ws[b * PP + p] = Dv / fmaxf(sqrtf(Ev) * sqrtf(Av), 1e-8f);
  }
}

// ---------------------------------------------------------------------------
// K7: out[bv,k] = hg[bv,:] @ w2[:,k] + b2[k], hg = sum_p gate[b,p]*h_all[gather]
// Block = (k-tile of 128, b-pair). Thread computes 8 bv x 8 k (4 LDS reads /
// 64 FMA per h — halves LDS-pipe clk per output vs 8x4). Grid (384,2) = 768
// blocks = 3/CU; LDS 43 KB -> 3 blocks/CU: LDS and VALU balanced (~384 clk/h).
// ---------------------------------------------------------------------------
__global__ __launch_bounds__(256) void k7_out(
    const float* __restrict__ w2, const float* __restrict__ b2,
    const float* __restrict__ h_all, const float* __restrict__ cos_ws,
    const int* __restrict__ prefix, float* __restrict__ out) {
  __shared__ float gate_lds[2][PP];
  __shared__ float hg_lds[2][HH * 64];   // [bsel][h][v], 21 KB
  __shared__ float w2_lds[HH * 128];     // [h][kk], 21.5 KB
  const int t = threadIdx.x;
  const int bp = blockIdx.y;             // b-pair: b = bp*2 + bsel
  const size_t kbase = (size_t)blockIdx.x * 128;
  for (int i = t; i < HH * 128; i += 256) {
    int h = i >> 7, kk = i & 127;
    w2_lds[i] = w2[(size_t)h * KK + kbase + kk];
  }
  if (t < 2) {
    const int b = bp * 2 + t;
    float c[PP];
    float m = -1e30f;
    #pragma unroll
    for (int p = 0; p < PP; ++p) { c[p] = cos_ws[b * PP + p]; m = fmaxf(m, c[p]); }
    float s = 0.0f;
    #pragma unroll
    for (int p = 0; p < PP; ++p) { c[p] = expf(c[p] - m); s += c[p]; }
    float inv = 1.0f / s;
    float m2 = -1e30f;
    #pragma unroll
    for (int p = 0; p < PP; ++p) { c[p] *= inv; m2 = fmaxf(m2, c[p]); }
    float s2 = 0.0f;
    #pragma unroll
    for (int p = 0; p < PP; ++p) { c[p] = expf(c[p] - m2); s2 += c[p]; }
    float inv2 = 1.0f / s2;
    #pragma unroll
    for (int p = 0; p < PP; ++p) gate_lds[t][p] = c[p] * inv2;
  }
  __syncthreads();
  for (int idx = t; idx < 2 * 64 * HH; idx += 256) {
    int bsel = (idx >= 64 * HH) ? 1 : 0;
    int local = idx - bsel * (64 * HH);
    int v = local & 63;
    int h = local >> 6;
    int tokv = prefix[(bp * 2 + bsel) * VV + v];
    float s = 0.0f;
    #pragma unroll
    for (int p = 0; p < PP; ++p)
      s += gate_lds[bsel][p] * h_all[(size_t)(p * VV + tokv) * HH + h];
    hg_lds[bsel][h * 64 + v] = s;
  }
  __syncthreads();
  const int tkg = t & 15;        // 16 k-groups of 8
  const int tbg = t >> 4;        // 16 bv-groups of 8
  const int bsel = tbg >> 3;     // which b of the pair
  const int v0 = (tbg & 7) * 8;  // 8 v rows within that b
  float4 acc[8][2];
  #pragma unroll
  for (int i = 0; i < 8; ++i) {
    acc[i][0] = make_float4(0.f, 0.f, 0.f, 0.f);
    acc[i][1] = make_float4(0.f, 0.f, 0.f, 0.f);
  }
  const float4* w24 = (const float4*)w2_lds;
  const float4* hg4 = (const float4*)hg_lds[bsel];
  #pragma unroll 2
  for (int h = 0; h < HH; ++h) {
    float4 w0 = w24[h * 32 + tkg * 2];
    float4 w1v = w24[h * 32 + tkg * 2 + 1];
    float4 g0 = hg4[h * 16 + (v0 >> 2)];
    float4 g1 = hg4[h * 16 + (v0 >> 2) + 1];
    float gg[8] = {g0.x, g0.y, g0.z, g0.w, g1.x, g1.y, g1.z, g1.w};
    #pragma unroll
    for (int i = 0; i < 8; ++i) {
      acc[i][0].x += gg[i] * w0.x;
      acc[i][0].y += gg[i] * w0.y;
      acc[i][0].z += gg[i] * w0.z;
      acc[i][0].w += gg[i] * w0.w;
      acc[i][1].x += gg[i] * w1v.x;
      acc[i][1].y += gg[i] * w1v.y;
      acc[i][1].z += gg[i] * w1v.z;
      acc[i][1].w += gg[i] * w1v.w;
    }
  }
  const float4* b24 = (const float4*)b2;
  float4 b2a = b24[(kbase >> 2) + tkg * 2];
  float4 b2b = b24[(kbase >> 2) + tkg * 2 + 1];
  float4* out4 = (float4*)out;
  const int b = bp * 2 + bsel;
  #pragma unroll
  for (int i = 0; i < 8; ++i) {
    int bv = b * 64 + v0 + i;
    size_t base = (((size_t)bv * KK + kbase) >> 2) + tkg * 2;
    float4 o0, o1;
    o0.x = acc[i][0].x + b2a.x; o0.y = acc[i][0].y + b2a.y;
    o0.z = acc[i][0].z + b2a.z; o0.w = acc[i][0].w + b2a.w;
    o1.x = acc[i][1].x + b2b.x; o1.y = acc[i][1].y + b2b.y;
    o1.z = acc[i][1].z + b2b.z; o1.w = acc[i][1].w + b2b.w;
    out4[base] = o0;
    out4[base + 1] = o1;
  }
}

extern "C" void kernel_launch(void* const* d_in, const int* in_sizes, int n_in,
                              void* d_out, int out_size, void* d_ws, size_t ws_size,
                              hipStream_t stream) {
  const int* prefix = (const int*)d_in[0];
  const float* ctx = (const float*)d_in[1];
  const float* tables = (const float*)d_in[2];
  const float* lora = (const float*)d_in[3];
  const float* w1 = (const float*)d_in[4];
  const float* b1 = (const float*)d_in[5];
  const float* w2 = (const float*)d_in[6];
  const float* b2 = (const float*)d_in[7];
  float* out = (float*)d_out;
  char* ws = (char*)d_ws;
  // workspace (bytes): part 8388608 | cos 128 | h_all 86016  (~8.5 MB)
  float* part = (float*)ws;
  float* cos_ws = (float*)(ws + 8388608);
  float* h_all = (float*)(ws + 8388608 + 128);

  kU_fused<<<dim3(192, 4), 512, 0, stream>>>(ctx, lora, tables, w1, b1, part, h_all);
  k4_cos<<<dim3(8, 4), 256, 0, stream>>>(part, lora, cos_ws);
  k7_out<<<dim3(384, 2), 256, 0, stream>>>(w2, b2, h_all, cos_ws, prefix, out);
}